// Round 8
// baseline (634.697 us; speedup 1.0000x reference)
//
#include <hip/hip_runtime.h>
#include <hip/hip_bf16.h>
#include <math.h>

// GCN link predictor: N=100000 nodes, d=128, E=1.6M edges, EL=200K label edges.
// Round 8 = Round 7 with the workspace-aliasing bug fixed: bincur@1792K sat
// inside cursor's [1536K, 1536K+400000B) range; bin_kern's bincur atomics
// corrupted cursor[65536..65648] -> fill2 wrote csr far out of bounds ->
// memory fault. Small arrays now live after csr (bsum@8704K, bincur@8712K).
//
// CSR build write-amp fix (from R7 theory): fill_kern's scattered 4B writes
// cost 107MB HBM WRITE (64B line per record). Two-phase dst-binning:
//   bin_kern:  LDS-staged binning by dst>>10 -> bulk ~full-line flushes,
//              packed 4B records (dstlow<<17 | src).
//   fill2_kern: bin-ordered -> csr, XCD-aware (blockIdx%8) so a bin's csr
//              region + cursors stay in ONE XCD's L2.
//
// Workspace layout (bytes):
//   0        dinv    float[N]      (400 KB)
//   512K     deg     int[N]        (400 KB)
//   1024K    row_off int[N+1]      (400 KB)
//   1536K    cursor  int[N]        (400 KB, ends 1,972,864)
//   2048K    csr     int[E]        (6.4 MB, ends ~8.5M)
//   8704K    bsum    int[128]
//   8712K    bincur  int[112]
//   10M      ebin    int[E]        (6.4 MB)
//   24M      hbuf    bf16[N*128]   (25.6 MB)
//   56M      zbuf    float[N*128]  (51.2 MB)   total ~110 MB (R2 proved >=119 MB ws)

#define WAVE 64
#define SCAN_CHUNK 1024   // elements per block (256 threads x 4)
#define GK 32             // gemm k-chunk
#define BSHIFT 10         // 1024 nodes per bin
#define MAXBINS 112
#define BINCAP 96
#define BIN_ROUND 24      // edges per thread per staging round (24*256 = 6144)

// ---- bf16 pack/unpack (RNE) ----
__device__ __forceinline__ unsigned bf16_rne(float f) {
    unsigned u = __float_as_uint(f);
    return (u + 0x7FFFu + ((u >> 16) & 1u)) >> 16;
}
__device__ __forceinline__ uint2 pack4_bf16(float4 v) {
    uint2 o;
    o.x = bf16_rne(v.x) | (bf16_rne(v.y) << 16);
    o.y = bf16_rne(v.z) | (bf16_rne(v.w) << 16);
    return o;
}
__device__ __forceinline__ float4 unpack4_bf16(uint2 p) {
    float4 o;
    o.x = __uint_as_float(p.x << 16);
    o.y = __uint_as_float(p.x & 0xFFFF0000u);
    o.z = __uint_as_float(p.y << 16);
    o.w = __uint_as_float(p.y & 0xFFFF0000u);
    return o;
}

__global__ __launch_bounds__(256) void zero2_kern(int* __restrict__ a,
                                                  int* __restrict__ b, int N) {
    int i = blockIdx.x * blockDim.x + threadIdx.x;
    if (i < N) { a[i] = 0; b[i] = 0; }
}

__global__ __launch_bounds__(256) void deg_count_kern(const int* __restrict__ dst,
                                                      int* __restrict__ deg, int E) {
    int i = blockIdx.x * blockDim.x + threadIdx.x;
    if (i < E) atomicAdd(&deg[dst[i]], 1);
}

__device__ __forceinline__ int load4_sum(const int* __restrict__ deg, int base, int N,
                                         int4* out) {
    int4 v = make_int4(0, 0, 0, 0);
    if (base + 3 < N) {
        v = ((const int4*)deg)[base >> 2];
    } else {
        if (base + 0 < N) v.x = deg[base + 0];
        if (base + 1 < N) v.y = deg[base + 1];
        if (base + 2 < N) v.z = deg[base + 2];
        if (base + 3 < N) v.w = deg[base + 3];
    }
    *out = v;
    return v.x + v.y + v.z + v.w;
}

// Per-block partial sums of deg.
__global__ __launch_bounds__(256) void scan_part_kern(const int* __restrict__ deg,
                                                      int* __restrict__ bsum, int N) {
    __shared__ int sdata[256];
    int t = threadIdx.x;
    int base = blockIdx.x * SCAN_CHUNK + t * 4;
    int4 v;
    int sum = load4_sum(deg, base, N, &v);
    sdata[t] = sum;
    __syncthreads();
#pragma unroll
    for (int off = 128; off > 0; off >>= 1) {
        if (t < off) sdata[t] += sdata[t + off];
        __syncthreads();
    }
    if (t == 0) bsum[blockIdx.x] = sdata[0];
}

// Single small block: exclusive scan of nb (<=128) block sums; row_off[N]=total.
__global__ __launch_bounds__(128) void scan_top_kern(int* __restrict__ bsum,
                                                     int* __restrict__ row_off,
                                                     int nb, int N) {
    __shared__ int sdata[128];
    int t = threadIdx.x;
    int own = (t < nb) ? bsum[t] : 0;
    sdata[t] = own;
    __syncthreads();
#pragma unroll
    for (int off = 1; off < 128; off <<= 1) {
        int v = sdata[t];
        int add = (t >= off) ? sdata[t - off] : 0;
        __syncthreads();
        sdata[t] = v + add;
        __syncthreads();
    }
    if (t < nb) bsum[t] = sdata[t] - own;   // exclusive
    if (t == 127) row_off[N] = sdata[127];  // total == E
}

// Re-scan locally, add block offset, write row_off + dinv.
__global__ __launch_bounds__(256) void scan_apply_kern(const int* __restrict__ deg,
                                                       const int* __restrict__ bsum,
                                                       int* __restrict__ row_off,
                                                       float* __restrict__ dinv, int N) {
    __shared__ int sdata[256];
    int t = threadIdx.x;
    int base = blockIdx.x * SCAN_CHUNK + t * 4;
    int4 v;
    int sum = load4_sum(deg, base, N, &v);
    sdata[t] = sum;
    __syncthreads();
#pragma unroll
    for (int off = 1; off < 256; off <<= 1) {
        int x = sdata[t];
        int add = (t >= off) ? sdata[t - off] : 0;
        __syncthreads();
        sdata[t] = x + add;
        __syncthreads();
    }
    int run = bsum[blockIdx.x] + sdata[t] - sum;  // global exclusive prefix
    if (base + 0 < N) { row_off[base + 0] = run; dinv[base + 0] = rsqrtf((float)(v.x + 1)); run += v.x; }
    if (base + 1 < N) { row_off[base + 1] = run; dinv[base + 1] = rsqrtf((float)(v.y + 1)); run += v.y; }
    if (base + 2 < N) { row_off[base + 2] = run; dinv[base + 2] = rsqrtf((float)(v.z + 1)); run += v.z; }
    if (base + 3 < N) { row_off[base + 3] = run; dinv[base + 3] = rsqrtf((float)(v.w + 1)); }
}

// bincur[k] = start of bin k's region in ebin (== row_off at bin boundary).
__global__ __launch_bounds__(128) void init_bincur_kern(const int* __restrict__ row_off,
                                                        int* __restrict__ bincur,
                                                        int nbins, int N) {
    int t = threadIdx.x;
    if (t < nbins) {
        int node = t << BSHIFT; if (node > N) node = N;
        bincur[t] = row_off[node];
    }
}

// Phase A: stream edges, stage packed records (dstlow<<17 | src) in LDS bins,
// flush in bulk (~63 records) bursts -> coalesced near-full-line writes.
// Overflow (rare, LDS cap) falls back to direct scatter.
__global__ __launch_bounds__(256) void bin_kern(const int* __restrict__ src,
                                                const int* __restrict__ dst,
                                                int* __restrict__ bincur,
                                                int* __restrict__ ebin,
                                                int E, int nbins, int nblocks) {
    __shared__ int cnt[MAXBINS];
    __shared__ int buf[MAXBINS][BINCAP];
    int tid = threadIdx.x;
    int per = (E + nblocks - 1) / nblocks;
    int e0 = blockIdx.x * per;
    int e1 = e0 + per; if (e1 > E) e1 = E;
    for (int i = tid; i < nbins; i += 256) cnt[i] = 0;
    __syncthreads();

    for (int start = e0; start < e1; start += BIN_ROUND * 256) {
        // staging phase
        for (int it = 0; it < BIN_ROUND; ++it) {
            int e = start + it * 256 + tid;
            if (e < e1) {
                int s = src[e], d = dst[e];
                int k = d >> BSHIFT;
                int rec = s | ((d & ((1 << BSHIFT) - 1)) << 17);
                int pos = atomicAdd(&cnt[k], 1);
                if (pos < BINCAP) buf[k][pos] = rec;
                else { int p = atomicAdd(&bincur[k], 1); ebin[p] = rec; }
            }
        }
        __syncthreads();
        // flush phase: wave w handles bins w, w+4, ...
        int wv = tid >> 6, ln = tid & 63;
        for (int k = wv; k < nbins; k += 4) {
            int m = cnt[k]; if (m > BINCAP) m = BINCAP;
            if (m > 0) {
                int base = 0;
                if (ln == 0) base = atomicAdd(&bincur[k], m);
                base = __shfl(base, 0, 64);
                for (int j = ln; j < m; j += 64) ebin[base + j] = buf[k][j];
                if (ln == 0) cnt[k] = 0;
            }
        }
        __syncthreads();
    }
}

// Phase B: bin-ordered records -> csr. XCD-aware: all 8 worker-blocks of a
// bin share blockIdx%8, so (heuristically) one XCD owns the bin's cursor +
// csr lines -> ~1x writeback. Grid = 8 * 13 * 8 = 832 blocks.
__global__ __launch_bounds__(256) void fill2_kern(const int* __restrict__ row_off,
                                                  const int* __restrict__ ebin,
                                                  int* __restrict__ cursor,
                                                  int* __restrict__ csr,
                                                  int N, int nbins) {
    int b = blockIdx.x;
    int xcd = b & 7;
    int r = b >> 3;          // 0..103
    int m = r % 13;
    int s = r / 13;          // slice 0..7
    int k = xcd + 8 * m;
    if (k >= nbins) return;
    int lo = k << BSHIFT;
    int hi = (k + 1) << BSHIFT; if (hi > N) hi = N;
    int binstart = row_off[lo];
    int len = row_off[hi] - binstart;
    int a   = binstart + (int)(((long long)len * s) >> 3);
    int bnd = binstart + (int)(((long long)len * (s + 1)) >> 3);
    for (int i = a + threadIdx.x; i < bnd; i += 256) {
        int rec = ebin[i];
        int sv = rec & 0x1FFFF;
        int d  = lo | (rec >> 17);
        int p = atomicAdd(&cursor[d], 1);
        csr[row_off[d] + p] = sv;
    }
}

// Fallback direct fill (used only if N too large for packed records).
__global__ __launch_bounds__(256) void fill_kern(const int* __restrict__ src,
                                                 const int* __restrict__ dst,
                                                 const int* __restrict__ row_off,
                                                 int* __restrict__ cursor,
                                                 int* __restrict__ csr, int E) {
    int e = blockIdx.x * blockDim.x + threadIdx.x;
    if (e >= E) return;
    int d = dst[e];
    int p = atomicAdd(&cursor[d], 1);
    csr[row_off[d] + p] = src[e];
}

// H[M,128](bf16) = X[M,128](fp32) @ W[128,128](fp32). 64 rows x 128 cols/block.
// K chunked by GK=32: LDS = 24 KB -> 6 blocks/CU.
__global__ __launch_bounds__(256) void gemm128_kern(const float* __restrict__ X,
                                                    const float* __restrict__ W,
                                                    uint2* __restrict__ H16, int M) {
    __shared__ float xs[64][GK];      // 8 KB
    __shared__ float wsm[GK][128];    // 16 KB
    int tid = threadIdx.x;
    int block_row = blockIdx.x * 64;
    int tx = tid & 31;
    int ty = tid >> 5;

    float4 acc[8];
#pragma unroll
    for (int i = 0; i < 8; ++i) acc[i] = make_float4(0.f, 0.f, 0.f, 0.f);

    for (int k0 = 0; k0 < 128; k0 += GK) {
        __syncthreads();  // protect previous chunk's LDS reads
        {
            const float4* W4 = (const float4*)(W + (size_t)k0 * 128);
            float4* w4 = (float4*)wsm;
#pragma unroll
            for (int i = 0; i < 4; ++i) w4[tid + 256 * i] = W4[tid + 256 * i];
        }
        {
#pragma unroll
            for (int i = 0; i < 2; ++i) {
                int idx = tid + 256 * i;   // 0..511
                int r = idx >> 3;          // 0..63
                int c = idx & 7;           // float4 within chunk
                int grow = block_row + r;
                float4 v = make_float4(0.f, 0.f, 0.f, 0.f);
                if (grow < M) v = ((const float4*)X)[(size_t)grow * 32 + (k0 >> 2) + c];
                ((float4*)xs)[idx] = v;
            }
        }
        __syncthreads();

#pragma unroll 4
        for (int kk = 0; kk < GK; ++kk) {
            float4 wv = ((float4*)&wsm[kk][0])[tx];
            float xr[8];
#pragma unroll
            for (int i = 0; i < 8; ++i) xr[i] = xs[ty * 8 + i][kk];
#pragma unroll
            for (int i = 0; i < 8; ++i) {
                acc[i].x = fmaf(xr[i], wv.x, acc[i].x);
                acc[i].y = fmaf(xr[i], wv.y, acc[i].y);
                acc[i].z = fmaf(xr[i], wv.z, acc[i].z);
                acc[i].w = fmaf(xr[i], wv.w, acc[i].w);
            }
        }
    }

#pragma unroll
    for (int i = 0; i < 8; ++i) {
        int grow = block_row + ty * 8 + i;
        if (grow < M) H16[(size_t)grow * 32 + tx] = pack4_bf16(acc[i]);
    }
}

// One wave per node, h in bf16 (256 B rows). 16-edge chunks: per-lane load
// src + dinv[src], shfl {src, norm}, 8 independent half-split uint2 gathers.
__global__ __launch_bounds__(256) void agg_kern(const int* __restrict__ row_off,
                                                const int* __restrict__ csr,
                                                const float* __restrict__ dinv,
                                                const uint2* __restrict__ h16,
                                                const float* __restrict__ bias,
                                                void* __restrict__ z,
                                                int N, int do_relu, int out_bf16) {
    int wave = (blockIdx.x * blockDim.x + threadIdx.x) >> 6;
    int lane = threadIdx.x & (WAVE - 1);
    if (wave >= N) return;
    int v = wave;
    int half = lane >> 5;    // lanes 0-31: even edge slots, 32-63: odd slots
    int l32 = lane & 31;
    int beg = row_off[v];
    int degv = row_off[v + 1] - beg;
    float dv = dinv[v];

    float4 acc = make_float4(0.f, 0.f, 0.f, 0.f);

    for (int base = 0; base < degv; base += WAVE) {
        int cnt = degv - base; if (cnt > WAVE) cnt = WAVE;
        int s_lane = 0;
        float n_lane = 0.f;
        if (lane < cnt) {
            s_lane = csr[beg + base + lane];       // coalesced
            n_lane = dinv[s_lane] * dv;            // dinv: 400 KB, L2-resident
        }
        for (int j = 0; j < cnt; j += 16) {
            int   sidx[8];
            float nn[8];
#pragma unroll
            for (int u = 0; u < 8; ++u) {
                int sl = j + 2 * u + half;          // slot in [j, j+16)
                sidx[u] = __shfl(s_lane, sl);
                nn[u]   = __shfl(n_lane, sl);
            }
            uint2 hv[8];
#pragma unroll
            for (int u = 0; u < 8; ++u)             // 8 independent 512 B gathers
                hv[u] = h16[(size_t)sidx[u] * 32 + l32];
#pragma unroll
            for (int u = 0; u < 8; ++u) {
                float4 f = unpack4_bf16(hv[u]);
                acc.x = fmaf(f.x, nn[u], acc.x);
                acc.y = fmaf(f.y, nn[u], acc.y);
                acc.z = fmaf(f.z, nn[u], acc.z);
                acc.w = fmaf(f.w, nn[u], acc.w);
            }
        }
    }

    // combine the two halves (lane^32)
    acc.x += __shfl_xor(acc.x, 32, 64);
    acc.y += __shfl_xor(acc.y, 32, 64);
    acc.z += __shfl_xor(acc.z, 32, 64);
    acc.w += __shfl_xor(acc.w, 32, 64);

    float ss = dv * dv;
    float4 hv = unpack4_bf16(h16[(size_t)v * 32 + l32]);
    float4 bv = ((const float4*)bias)[l32];
    acc.x = fmaf(hv.x, ss, acc.x) + bv.x;
    acc.y = fmaf(hv.y, ss, acc.y) + bv.y;
    acc.z = fmaf(hv.z, ss, acc.z) + bv.z;
    acc.w = fmaf(hv.w, ss, acc.w) + bv.w;
    if (do_relu) {
        acc.x = fmaxf(acc.x, 0.f); acc.y = fmaxf(acc.y, 0.f);
        acc.z = fmaxf(acc.z, 0.f); acc.w = fmaxf(acc.w, 0.f);
    }
    if (half == 0) {
        if (out_bf16) ((uint2*)z)[(size_t)v * 32 + l32] = pack4_bf16(acc);
        else          ((float4*)z)[(size_t)v * 32 + l32] = acc;
    }
}

// Four label edges per wave (2 per half-wave), z2 in bf16 (256 B rows).
__global__ __launch_bounds__(256) void decode_kern(const int* __restrict__ s_idx,
                                                   const int* __restrict__ d_idx,
                                                   const uint2* __restrict__ z16,
                                                   float* __restrict__ out, int EL) {
    int lane = threadIdx.x & (WAVE - 1);
    int wave = (blockIdx.x * blockDim.x + threadIdx.x) >> 6;
    int half = lane >> 5;
    int l32 = lane & 31;
    int e0 = wave * 4 + half;      // this half-wave handles e0 and e0+2
    int e1 = e0 + 2;

    int s0 = 0, d0 = 0, s1 = 0, d1 = 0;
    if (e0 < EL) { s0 = s_idx[e0]; d0 = d_idx[e0]; }
    if (e1 < EL) { s1 = s_idx[e1]; d1 = d_idx[e1]; }
    uint2 pa0 = z16[(size_t)s0 * 32 + l32];
    uint2 pb0 = z16[(size_t)d0 * 32 + l32];
    uint2 pa1 = z16[(size_t)s1 * 32 + l32];
    uint2 pb1 = z16[(size_t)d1 * 32 + l32];
    float4 a0 = unpack4_bf16(pa0), b0 = unpack4_bf16(pb0);
    float4 a1 = unpack4_bf16(pa1), b1 = unpack4_bf16(pb1);
    float p0 = a0.x * b0.x + a0.y * b0.y + a0.z * b0.z + a0.w * b0.w;
    float p1 = a1.x * b1.x + a1.y * b1.y + a1.z * b1.z + a1.w * b1.w;
#pragma unroll
    for (int off = 16; off > 0; off >>= 1) {
        p0 += __shfl_xor(p0, off, 64);   // stays within the 32-lane half
        p1 += __shfl_xor(p1, off, 64);
    }
    if (l32 == 0) {
        if (e0 < EL) out[e0] = p0;
        if (e1 < EL) out[e1] = p1;
    }
}

extern "C" void kernel_launch(void* const* d_in, const int* in_sizes, int n_in,
                              void* d_out, int out_size, void* d_ws, size_t ws_size,
                              hipStream_t stream) {
    const float* x   = (const float*)d_in[0];
    const int*   ei  = (const int*)d_in[1];
    const int*   eli = (const int*)d_in[2];
    const float* W1  = (const float*)d_in[3];
    const float* b1  = (const float*)d_in[4];
    const float* W2  = (const float*)d_in[5];
    const float* b2  = (const float*)d_in[6];
    float* out = (float*)d_out;

    int N  = in_sizes[0] / 128;
    int E  = in_sizes[1] / 2;
    int EL = in_sizes[2] / 2;
    const int* src = ei;
    const int* dst = ei + E;
    const int* ls  = eli;
    const int* ld  = eli + EL;

    char* ws = (char*)d_ws;
    float* dinv    = (float*)(ws);
    int*   deg     = (int*)(ws + (512 << 10));
    int*   row_off = (int*)(ws + (1024 << 10));
    int*   cursor  = (int*)(ws + (1536 << 10));   // ends at 1536K+400000 < 2048K
    int*   csr     = (int*)(ws + (2048 << 10));   // ends ~8.5 MB
    int*   bsum    = (int*)(ws + (8704 << 10));   // past csr
    int*   bincur  = (int*)(ws + (8712 << 10));
    int*   ebin    = (int*)(ws + (10u << 20));
    uint2* hbuf    = (uint2*)(ws + (24u << 20));  // bf16 h (25.6 MB)
    char*  zraw    = ws + (56u << 20);            // z1 fp32 / z2 bf16 (51.2 MB)
    float* z1      = (float*)zraw;
    uint2* z2      = (uint2*)zraw;

    int nodeGrid = (N + 255) / 256;
    int edgeGrid = (E + 255) / 256;
    int gemmGrid = (N + 63) / 64;
    int aggGrid  = (N + 3) / 4;   // 4 waves/block, 1 wave/node
    int nbScan   = (N + SCAN_CHUNK - 1) / SCAN_CHUNK;  // 98 for N=100K (<=128)
    int nbins    = (N + (1 << BSHIFT) - 1) >> BSHIFT;  // 98 for N=100K

    // CSR build (shared by both layers)
    zero2_kern<<<nodeGrid, 256, 0, stream>>>(deg, cursor, N);
    deg_count_kern<<<edgeGrid, 256, 0, stream>>>(dst, deg, E);
    scan_part_kern<<<nbScan, 256, 0, stream>>>(deg, bsum, N);
    scan_top_kern<<<1, 128, 0, stream>>>(bsum, row_off, nbScan, N);
    scan_apply_kern<<<nbScan, 256, 0, stream>>>(deg, bsum, row_off, dinv, N);

    if (nbins <= MAXBINS && N <= (1 << 17)) {
        int nBinBlocks = 128;
        init_bincur_kern<<<1, 128, 0, stream>>>(row_off, bincur, nbins, N);
        bin_kern<<<nBinBlocks, 256, 0, stream>>>(src, dst, bincur, ebin, E, nbins, nBinBlocks);
        fill2_kern<<<832, 256, 0, stream>>>(row_off, ebin, cursor, csr, N, nbins);
    } else {
        fill_kern<<<edgeGrid, 256, 0, stream>>>(src, dst, row_off, cursor, csr, E);
    }

    // layer 1: h1(bf16) = x @ W1 ; z1(fp32) = relu(agg(h1) + b1)
    gemm128_kern<<<gemmGrid, 256, 0, stream>>>(x, W1, hbuf, N);
    agg_kern<<<aggGrid, 256, 0, stream>>>(row_off, csr, dinv, hbuf, b1, (void*)z1, N, 1, 0);

    // layer 2: h2(bf16) = z1 @ W2 ; z2(bf16) = agg(h2) + b2
    gemm128_kern<<<gemmGrid, 256, 0, stream>>>(z1, W2, hbuf, N);
    agg_kern<<<aggGrid, 256, 0, stream>>>(row_off, csr, dinv, hbuf, b2, (void*)z2, N, 0, 1);

    // decode: 4 edges per wave, bf16 gathers
    decode_kern<<<(EL + 15) / 16, 256, 0, stream>>>(ls, ld, z2, out, EL);
}